// Round 7
// baseline (258.838 us; speedup 1.0000x reference)
//
#include <hip/hip_runtime.h>
#include <math.h>

// MS-SSIM loss, 5 levels, 11x11 separable Gaussian, zero padding.
// R7: vertical-first separable conv. Each lane loads ONLY its own column
// (2 dword loads/row, 1-row software prefetch), keeps raw fields
// (a, b, a^2, b^2) in a named-scalar register ring, v-convolves (44 FMA),
// then h-convolves the v-result via ds_bpermute pulls from neighbor lanes
// (10 taps x 4 fields, precomputed indices). Replaces R5's 22 loads + 88
// h-conv VALU per row; halo rows are now ~8 instr (no h-conv). Zero padding
// falls out of per-lane column guards. chunkH=32 divides every level H.

#define NIMG 48            // 16 * 3
#define OUTW 52            // output columns per strip (64 = 6 + 52 + 6)
#define CH 32              // chunk height; divides 512,256,128,64,32
#define TWO_C1 2.0e-4f     // 2 * (0.01*1.0)^2
#define TWO_C2 1.8e-3f     // 2 * (0.03*1.0)^2

struct CInfo { int base[5]; int cnt[5]; };

#define FOR11(X) X(0) X(1) X(2) X(3) X(4) X(5) X(6) X(7) X(8) X(9) X(10)

#define DECLR(K) float rA##K = 0.f, rB##K = 0.f, rP##K = 0.f, rQ##K = 0.f;
#define DECLIDX(K) const int ix##K = (lane + (K) - 5) * 4;

__device__ __forceinline__ float bperm_f(int idx, float v) {
  return __int_as_float(__builtin_amdgcn_ds_bpermute(idx, __float_as_int(v)));
}

// One input row R: consume prefetched (pN,tN), prefetch row R+1, store raw
// fields into ring slot SW (literal), fused 2x2 avg-pool on own column.
#define MS_STEP_N(R, SW) do { \
    const int r_ = (R); \
    const float pC = pN, tC = tN; \
    { const int rn_ = r_ + 1; \
      pN = 0.f; tN = 0.f; \
      if (((unsigned)rn_ < (unsigned)H) && colv) { \
        const size_t ro_ = (size_t)rn_ * W + (size_t)gx; \
        pN = Pi[ro_]; tN = Ti[ro_]; \
      } } \
    const float aC = pC + tC, bC = pC - tC; \
    rA##SW = aC; rB##SW = bC; rP##SW = aC * aC; rQ##SW = bC * bC; \
    if (DS) { \
      if (r_ >= y0 && r_ < y0 + CH) { \
        if ((r_ & 1) == 0) { pr = pC; tr = tC; } \
        else { \
          float sp_ = pr + pC, st_ = tr + tC; \
          sp_ += __shfl_xor(sp_, 1, 64); \
          st_ += __shfl_xor(st_, 1, 64); \
          if (((lane & 1) == 0) && outl) { \
            const size_t o_ = obase + (size_t)(r_ >> 1) * (size_t)(W >> 1) + \
                              (size_t)(gx >> 1); \
            dsP[o_] = sp_ * 0.25f; \
            dsT[o_] = st_ * 0.25f; \
          } } } } \
  } while (0)

#define VSTEP(GK, S) \
    vA_ = __builtin_fmaf(GK, rA##S, vA_); vB_ = __builtin_fmaf(GK, rB##S, vB_); \
    vP_ = __builtin_fmaf(GK, rP##S, vP_); vQ_ = __builtin_fmaf(GK, rQ##S, vQ_);

#define HTAP(K) { \
    const float ta_ = bperm_f(ix##K, vA_); \
    const float tb_ = bperm_f(ix##K, vB_); \
    const float tp_ = bperm_f(ix##K, vP_); \
    const float tq_ = bperm_f(ix##K, vQ_); \
    hA_ = __builtin_fmaf(G##K, ta_, hA_); \
    hB_ = __builtin_fmaf(G##K, tb_, hB_); \
    hP_ = __builtin_fmaf(G##K, tp_, hP_); \
    hQ_ = __builtin_fmaf(G##K, tq_, hQ_); }

// One output row IROW (0-based in chunk). SW = write slot (row IROW+10 of
// window); S0..S10 = slots of rows IROW-5..IROW+5 relative to y0-5.
#define ROW_N(IROW, SW, S0,S1,S2,S3,S4,S5,S6,S7,S8,S9,S10) do { \
    MS_STEP_N(y0 + 5 + (IROW), SW); \
    float vA_ = G0 * rA##S0, vB_ = G0 * rB##S0; \
    float vP_ = G0 * rP##S0, vQ_ = G0 * rQ##S0; \
    VSTEP(G1, S1) VSTEP(G2, S2) VSTEP(G3, S3) VSTEP(G4, S4) VSTEP(G5, S5) \
    VSTEP(G6, S6) VSTEP(G7, S7) VSTEP(G8, S8) VSTEP(G9, S9) VSTEP(G10, S10) \
    float hA_ = G5 * vA_, hB_ = G5 * vB_, hP_ = G5 * vP_, hQ_ = G5 * vQ_; \
    HTAP(0) HTAP(1) HTAP(2) HTAP(3) HTAP(4) \
    HTAP(6) HTAP(7) HTAP(8) HTAP(9) HTAP(10) \
    const float A2_ = hA_ * hA_, B2_ = hB_ * hB_; \
    const float dAB_ = A2_ - B2_, sAB_ = A2_ + B2_; \
    const float cn_ = (hP_ - hQ_) - dAB_ + TWO_C2; \
    const float cd_ = (hP_ + hQ_) - sAB_ + TWO_C2; \
    float val_; \
    if (LAST) val_ = ((dAB_ + TWO_C1) * cn_) / ((sAB_ + TWO_C1) * cd_); \
    else      val_ = cn_ / cd_; \
    if (outl) sum += val_; \
  } while (0)

#define BLOCK11(BASE) \
    ROW_N((BASE) + 0, 10, 0,1,2,3,4,5,6,7,8,9,10); \
    ROW_N((BASE) + 1, 0,  1,2,3,4,5,6,7,8,9,10,0); \
    ROW_N((BASE) + 2, 1,  2,3,4,5,6,7,8,9,10,0,1); \
    ROW_N((BASE) + 3, 2,  3,4,5,6,7,8,9,10,0,1,2); \
    ROW_N((BASE) + 4, 3,  4,5,6,7,8,9,10,0,1,2,3); \
    ROW_N((BASE) + 5, 4,  5,6,7,8,9,10,0,1,2,3,4); \
    ROW_N((BASE) + 6, 5,  6,7,8,9,10,0,1,2,3,4,5); \
    ROW_N((BASE) + 7, 6,  7,8,9,10,0,1,2,3,4,5,6); \
    ROW_N((BASE) + 8, 7,  8,9,10,0,1,2,3,4,5,6,7); \
    ROW_N((BASE) + 9, 8,  9,10,0,1,2,3,4,5,6,7,8); \
    ROW_N((BASE) + 10, 9, 10,0,1,2,3,4,5,6,7,8,9);

#define BLOCK10(BASE) \
    ROW_N((BASE) + 0, 10, 0,1,2,3,4,5,6,7,8,9,10); \
    ROW_N((BASE) + 1, 0,  1,2,3,4,5,6,7,8,9,10,0); \
    ROW_N((BASE) + 2, 1,  2,3,4,5,6,7,8,9,10,0,1); \
    ROW_N((BASE) + 3, 2,  3,4,5,6,7,8,9,10,0,1,2); \
    ROW_N((BASE) + 4, 3,  4,5,6,7,8,9,10,0,1,2,3); \
    ROW_N((BASE) + 5, 4,  5,6,7,8,9,10,0,1,2,3,4); \
    ROW_N((BASE) + 6, 5,  6,7,8,9,10,0,1,2,3,4,5); \
    ROW_N((BASE) + 7, 6,  7,8,9,10,0,1,2,3,4,5,6); \
    ROW_N((BASE) + 8, 7,  8,9,10,0,1,2,3,4,5,6,7); \
    ROW_N((BASE) + 9, 8,  9,10,0,1,2,3,4,5,6,7,8);

template <int DS, int LAST>
__global__ __launch_bounds__(256, 4)
void msssim_level_k(const float* __restrict__ P, const float* __restrict__ T,
                    const int H, const int W, const int strips,
                    const int chunks, const int tasks,
                    float* __restrict__ dsP, float* __restrict__ dsT,
                    double* __restrict__ partial,
                    const float G0, const float G1, const float G2,
                    const float G3, const float G4, const float G5,
                    const float G6, const float G7, const float G8,
                    const float G9, const float G10) {
  __shared__ float sRed[4];
  const int tid = threadIdx.x;
  const int lane = tid & 63;
  const int wid = tid >> 6;
  float sum = 0.f;
  const int task = blockIdx.x * 4 + wid;
  if (task < tasks) {
    const int strip = task % strips;
    const int rem = task / strips;
    const int chunk = rem % chunks;
    const int img = rem / chunks;
    const int y0 = chunk * CH;
    const int gx = strip * OUTW + lane - 6;           // even strip offset
    const bool colv = ((unsigned)gx < (unsigned)W);
    const bool outl = (lane >= 6) && (lane < 58) && colv;
    const float* Pi = P + (size_t)img * H * W;
    const float* Ti = T + (size_t)img * H * W;
    const size_t obase = DS ? (size_t)img * (size_t)(H >> 1) * (W >> 1) : 0;

    FOR11(DECLR)                 // ring: rA0..rQ10, named scalars
    FOR11(DECLIDX)               // bpermute byte indices ix0..ix10
    float pr = 0.f, tr = 0.f;
    float pN = 0.f, tN = 0.f;    // 1-row software prefetch

    {  // preload row y0-5
      const int r0 = y0 - 5;
      if (((unsigned)r0 < (unsigned)H) && colv) {
        const size_t ro = (size_t)r0 * W + (size_t)gx;
        pN = Pi[ro]; tN = Ti[ro];
      }
    }

    // Prologue: slots 0..9 <- rows y0-5 .. y0+4 (cheap: no conv).
    MS_STEP_N(y0 - 5, 0); MS_STEP_N(y0 - 4, 1); MS_STEP_N(y0 - 3, 2);
    MS_STEP_N(y0 - 2, 3); MS_STEP_N(y0 - 1, 4); MS_STEP_N(y0 + 0, 5);
    MS_STEP_N(y0 + 1, 6); MS_STEP_N(y0 + 2, 7); MS_STEP_N(y0 + 3, 8);
    MS_STEP_N(y0 + 4, 9);

    // 32 output rows: 11 + 11 + 10 phases (CH == 32).
    BLOCK11(0)
    BLOCK11(11)
    BLOCK10(22)
  }

#pragma unroll
  for (int off = 32; off; off >>= 1) sum += __shfl_down(sum, off, 64);
  if (lane == 0) sRed[wid] = sum;
  __syncthreads();
  if (tid == 0)
    partial[blockIdx.x] = (double)(sRed[0] + sRed[1] + sRed[2] + sRed[3]);
}

__global__ void msssim_combine_k(const double* __restrict__ partial,
                                 float* __restrict__ out, const CInfo ci) {
  const int lane = threadIdx.x & 63;
  double lv[5];
#pragma unroll
  for (int L = 0; L < 5; ++L) {
    double s = 0.0;
    for (int i = lane; i < ci.cnt[L]; i += 64) s += partial[ci.base[L] + i];
#pragma unroll
    for (int off = 32; off; off >>= 1) s += __shfl_down(s, off, 64);
    lv[L] = s;
  }
  if (lane == 0) {
    double ms = lv[4] / (48.0 * 32.0 * 32.0);
    ms *= pow(lv[0] / (48.0 * 512.0 * 512.0), (double)0.0448f);
    ms *= pow(lv[1] / (48.0 * 256.0 * 256.0), (double)0.2856f);
    ms *= pow(lv[2] / (48.0 * 128.0 * 128.0), (double)0.3001f);
    ms *= pow(lv[3] / (48.0 * 64.0 * 64.0),  (double)0.2363f);
    out[0] = (float)(1.0 - ms);
  }
}

extern "C" void kernel_launch(void* const* d_in, const int* in_sizes, int n_in,
                              void* d_out, int out_size, void* d_ws, size_t ws_size,
                              hipStream_t stream) {
  const float* pred = (const float*)d_in[0];
  const float* targ = (const float*)d_in[1];
  float* out = (float*)d_out;

  char* ws = (char*)d_ws;
  double* partial = (double*)ws;  // per-block partial sums, 32KB region
  size_t off = 32768;
  auto alloc = [&](size_t elems) {
    float* p = (float*)(ws + off);
    off += elems * sizeof(float);
    return p;
  };
  float* L1p = alloc((size_t)NIMG * 256 * 256);
  float* L1t = alloc((size_t)NIMG * 256 * 256);
  float* L2p = alloc((size_t)NIMG * 128 * 128);
  float* L2t = alloc((size_t)NIMG * 128 * 128);
  float* L3p = alloc((size_t)NIMG * 64 * 64);
  float* L3t = alloc((size_t)NIMG * 64 * 64);
  float* L4p = alloc((size_t)NIMG * 32 * 32);
  float* L4t = alloc((size_t)NIMG * 32 * 32);

  float g[11];
  {
    double gd[11], s = 0.0;
    for (int k = 0; k < 11; ++k) {
      const double c = (double)(k - 5);
      gd[k] = exp(-(c * c) / 4.5);  // 2*sigma^2 = 4.5
      s += gd[k];
    }
    for (int k = 0; k < 11; ++k) g[k] = (float)(gd[k] / s);
  }

  CInfo ci;
  int slotOff = 0;

  auto launchLevel = [&](const float* P, const float* T, int H, int W,
                         float* dP, float* dT, int L, bool last) {
    const int strips = (W + OUTW - 1) / OUTW;
    const int chunks = H / CH;
    const int tasks = strips * chunks * NIMG;
    const int blocks = (tasks + 3) / 4;
    ci.base[L] = slotOff;
    ci.cnt[L] = blocks;
    if (last) {
      msssim_level_k<0, 1><<<blocks, 256, 0, stream>>>(
          P, T, H, W, strips, chunks, tasks, nullptr, nullptr,
          partial + slotOff, g[0], g[1], g[2], g[3], g[4], g[5], g[6], g[7],
          g[8], g[9], g[10]);
    } else {
      msssim_level_k<1, 0><<<blocks, 256, 0, stream>>>(
          P, T, H, W, strips, chunks, tasks, dP, dT,
          partial + slotOff, g[0], g[1], g[2], g[3], g[4], g[5], g[6], g[7],
          g[8], g[9], g[10]);
    }
    slotOff += blocks;
  };

  launchLevel(pred, targ, 512, 512, L1p, L1t, 0, false);
  launchLevel(L1p, L1t, 256, 256, L2p, L2t, 1, false);
  launchLevel(L2p, L2t, 128, 128, L3p, L3t, 2, false);
  launchLevel(L3p, L3t, 64, 64, L4p, L4t, 3, false);
  launchLevel(L4p, L4t, 32, 32, nullptr, nullptr, 4, true);

  msssim_combine_k<<<1, 64, 0, stream>>>(partial, out, ci);
}